// Round 17
// baseline (247.470 us; speedup 1.0000x reference)
//
#include <hip/hip_runtime.h>
#include <math.h>

#define N_ROWS 262144
#define DIM 64
#define K_CODES 1024
#define NT 64                 // code tiles of 16
#define ROWS_PER_BLOCK 128
#define EPSF 1e-12f
#define MARGIN 2.0e-3f        // 2*E, E = rigorous hh-score error bound (9.9e-4)

typedef _Float16 f16x8 __attribute__((ext_vector_type(8)));
typedef _Float16 f16x4 __attribute__((ext_vector_type(4)));
typedef float f32x4 __attribute__((ext_vector_type(4)));

// ws layout (floats):
//   wn      : [0, 65536)           normalized codebook fp32
//   msw     : [65536, 66560)       -0.5 * sum(wn^2) per code
//   partial : [66560, 68608)       per-main-block loss partials (2048)
//   partial2: [68608, 68864)       per-fixup-block loss deltas (256)
//   counter : [68864]              (int) flagged-row count
//   list    : [68865, 331009)      (int) flagged row ids
//   wf      : from 331012          codebook hi/lo f16, 16x16x32 B-frag order
//             per 16-code tile t: 2048 halves:
//               [0,512)=hi s0 [512,1024)=hi s1 [1024,1536)=lo s0 [1536,2048)=lo s1
//             within each 512: lane(= g*16 + code%16)*8 + i, k-dim = s*32+g*8+i
//             +4 uninitialized guard tiles (prefetch targets, never consumed)

__global__ void init_kernel(int* counter) {
    if (threadIdx.x == 0) *counter = 0;
}

__global__ __launch_bounds__(64) void prep_codebook(
    const float* __restrict__ w, float* __restrict__ wn,
    float* __restrict__ msw, _Float16* __restrict__ wf)
{
    int k = blockIdx.x;
    int d = threadIdx.x;
    float v = w[k * DIM + d];
    float sq = v * v;
    #pragma unroll
    for (int off = 32; off; off >>= 1) sq += __shfl_xor(sq, off, 64);
    float n = fmaxf(sqrtf(sq), EPSF);
    float o = v / n;
    wn[k * DIM + d] = o;
    float s2 = o * o;
    #pragma unroll
    for (int off = 32; off; off >>= 1) s2 += __shfl_xor(s2, off, 64);
    if (d == 0) msw[k] = -0.5f * s2;

    _Float16 hi = (_Float16)o;
    _Float16 lo = (_Float16)(o - (float)hi);
    int t = k >> 4, nn = k & 15, s = d >> 5, g = (d >> 3) & 3, i = d & 7;
    size_t base = (size_t)t * 2048 + (size_t)s * 512 + (size_t)(g * 16 + nn) * 8 + i;
    wf[base] = hi;            // h = 0
    wf[base + 1024] = lo;     // h = 1
}

#define MFMA_(A, B, C) C = __builtin_amdgcn_mfma_f32_16x16x32_f16(A, B, C, 0, 0, 0)

// ------------------- main kernel: hi*hi prefilter -------------------
__global__ __launch_bounds__(256, 5) void vq_main_kernel(
    const float* __restrict__ x,
    const float* __restrict__ wn,
    const float* __restrict__ msw,
    const _Float16* __restrict__ wf,
    float* __restrict__ out_q,
    float* __restrict__ out_idx,
    float* __restrict__ partial,
    int* __restrict__ counter,
    int* __restrict__ list)
{
    __shared__ _Float16 bbuf[2][1024];        // double-buffered 2 KB hi tiles
    __shared__ float msw_lds[K_CODES];
    __shared__ int idx_lds[ROWS_PER_BLOCK];
    __shared__ float inv_lds[ROWS_PER_BLOCK];
    __shared__ float red[4];

    const int tid = threadIdx.x;              // 0..255 (4 waves)
    const int wv = tid >> 6;
    const int lane = tid & 63;
    const int nidx = lane & 15;
    const int g = lane >> 4;
    const int block_row0 = blockIdx.x * ROWS_PER_BLOCK;

    // ---- prologue: 32 rows/wave, normalize, hi A-frags only ----
    f16x8 ah[2][2];
    #pragma unroll
    for (int rt = 0; rt < 2; ++rt) {
        const int arow = block_row0 + wv * 32 + rt * 16 + nidx;
        const float* xrow = x + (size_t)arow * DIM + g * 8;
        float xv[2][8];
        #pragma unroll
        for (int s = 0; s < 2; ++s) {
            float4 q0 = *(const float4*)(xrow + s * 32);
            float4 q1 = *(const float4*)(xrow + s * 32 + 4);
            xv[s][0] = q0.x; xv[s][1] = q0.y; xv[s][2] = q0.z; xv[s][3] = q0.w;
            xv[s][4] = q1.x; xv[s][5] = q1.y; xv[s][6] = q1.z; xv[s][7] = q1.w;
        }
        float ss = 0.f;
        #pragma unroll
        for (int s = 0; s < 2; ++s)
            #pragma unroll
            for (int i = 0; i < 8; ++i) ss += xv[s][i] * xv[s][i];
        ss += __shfl_xor(ss, 16, 64);
        ss += __shfl_xor(ss, 32, 64);
        float nrm = fmaxf(sqrtf(ss), EPSF);
        float inv = 1.0f / nrm;
        if (g == 0) inv_lds[wv * 32 + rt * 16 + nidx] = inv;
        #pragma unroll
        for (int s = 0; s < 2; ++s)
            #pragma unroll
            for (int i = 0; i < 8; ++i)
                ah[rt][s][i] = (_Float16)(xv[s][i] * inv);
    }

    // ---- stage msw into LDS ----
    *(float4*)&msw_lds[tid * 4] = *(const float4*)(msw + tid * 4);

    // ---- stage hi of tile 0 into bbuf[0]; prefetch hi of tile 1 ----
    const _Float16* gsrc = wf + (size_t)tid * 4;   // 8B/thread, hi region
    {
        f16x4 s0 = *(const f16x4*)(gsrc);
        *(f16x4*)&bbuf[0][tid * 4] = s0;
    }
    f16x4 stg = *(const f16x4*)(gsrc + 2048);
    gsrc += 2 * 2048;
    __syncthreads();

    float b1v[2][4], b2v[2][4];
    int bti[2][4];
    #pragma unroll
    for (int rt = 0; rt < 2; ++rt)
        #pragma unroll
        for (int r = 0; r < 4; ++r) {
            b1v[rt][r] = -3.4e38f; b2v[rt][r] = -3.4e38f; bti[rt][r] = 0;
        }

    // ---- main loop: 64 tiles, hh only (4 MFMA/tile), top-2 tracking ----
    for (int t = 0; t < NT; ++t) {
        const int cur = t & 1;
        const _Float16* bp = &bbuf[cur][lane * 8];
        f16x8 b0 = *(const f16x8*)(bp);
        f16x8 b1 = *(const f16x8*)(bp + 512);
        float mval = msw_lds[t * 16 + nidx];

        f32x4 acc0 = {mval, mval, mval, mval};
        f32x4 acc1 = acc0;
        MFMA_(ah[0][0], b0, acc0); MFMA_(ah[1][0], b0, acc1);
        MFMA_(ah[0][1], b1, acc0); MFMA_(ah[1][1], b1, acc1);

        if (t + 1 < NT) {
            *(f16x4*)&bbuf[cur ^ 1][tid * 4] = stg;
            if (t + 2 < NT) {
                stg = *(const f16x4*)(gsrc);
                gsrc += 2048;
            }
        }

        // top-2 update (strict > keeps first index)
        #pragma unroll
        for (int r = 0; r < 4; ++r) {
            float s0 = acc0[r], s1 = acc1[r];
            b2v[0][r] = fmaxf(b2v[0][r], fminf(s0, b1v[0][r]));
            if (s0 > b1v[0][r]) { b1v[0][r] = s0; bti[0][r] = t; }
            b2v[1][r] = fmaxf(b2v[1][r], fminf(s1, b1v[1][r]));
            if (s1 > b1v[1][r]) { b1v[1][r] = s1; bti[1][r] = t; }
        }
        __syncthreads();
    }

    // ---- top-2 butterfly across the 16 lanes holding each row ----
    #pragma unroll
    for (int rt = 0; rt < 2; ++rt)
        #pragma unroll
        for (int r = 0; r < 4; ++r) {
            float b1 = b1v[rt][r], b2 = b2v[rt][r];
            int i1 = bti[rt][r] * 16 + nidx;
            #pragma unroll
            for (int off = 1; off <= 8; off <<= 1) {
                float ob1 = __shfl_xor(b1, off, 64);
                int   oi1 = __shfl_xor(i1, off, 64);
                float ob2 = __shfl_xor(b2, off, 64);
                float loser = fminf(b1, ob1);
                b2 = fmaxf(fmaxf(b2, ob2), loser);
                if (ob1 > b1 || (ob1 == b1 && oi1 < i1)) { b1 = ob1; i1 = oi1; }
            }
            if (nidx == 0) {
                const int lrow = wv * 32 + rt * 16 + g * 4 + r;
                idx_lds[lrow] = i1;
                if (b1 - b2 <= MARGIN) {          // ambiguous: exact fixup
                    int pos = atomicAdd(counter, 1);
                    list[pos] = block_row0 + lrow;
                }
            }
        }
    __syncthreads();

    // ---- epilogue: gather fp32 codebook row, write out, loss partial ----
    const int lr = tid >> 1;
    const int grow = block_row0 + lr;
    const int d0 = (tid & 1) * 32;
    const int ci = idx_lds[lr];
    const float invn = inv_lds[lr];
    const float4* xp = (const float4*)(x + (size_t)grow * DIM + d0);
    const float4* qp = (const float4*)(wn + (size_t)ci * DIM + d0);
    float4* op = (float4*)(out_q + (size_t)grow * DIM + d0);
    float ls = 0.f;
    #pragma unroll
    for (int i = 0; i < 8; ++i) {
        float4 qv = qp[i];
        float4 xv4 = xp[i];
        float e0 = qv.x - xv4.x * invn;
        float e1 = qv.y - xv4.y * invn;
        float e2 = qv.z - xv4.z * invn;
        float e3 = qv.w - xv4.w * invn;
        ls += e0 * e0 + e1 * e1 + e2 * e2 + e3 * e3;
        op[i] = qv;
    }
    if (!(tid & 1)) out_idx[grow] = (float)ci;

    float s = ls;
    #pragma unroll
    for (int off = 32; off; off >>= 1) s += __shfl_xor(s, off, 64);
    if (lane == 0) red[wv] = s;
    __syncthreads();
    if (tid == 0) partial[blockIdx.x] = (red[0] + red[1]) + (red[2] + red[3]);
}

// ------------------- fixup: exact 3-pass rescore of flagged rows -------------------
__global__ __launch_bounds__(256, 4) void fixup_kernel(
    const float* __restrict__ x,
    const float* __restrict__ wn,
    const float* __restrict__ msw,
    const _Float16* __restrict__ wf,
    const int* __restrict__ counter,
    const int* __restrict__ list,
    float* __restrict__ out_q,
    float* __restrict__ out_idx,
    float* __restrict__ partial2)
{
    __shared__ int rows_lds[128];
    __shared__ int idx_lds[128];
    __shared__ float inv_lds[128];
    __shared__ float red[4];

    const int tid = threadIdx.x;
    const int wv = tid >> 6;
    const int lane = tid & 63;
    const int nidx = lane & 15;
    const int g = lane >> 4;
    const int cnt = *counter;
    float dsum = 0.f;

    for (int b = blockIdx.x; b * 128 < cnt; b += gridDim.x) {
        const int rbase = b * 128;
        const int nrows = min(128, cnt - rbase);
        __syncthreads();
        if (tid < 128) rows_lds[tid] = list[rbase + min(tid, nrows - 1)];
        __syncthreads();

        // prologue: gather 32 rows/wave, hi+lo A-frags
        f16x8 ah[2][2], al[2][2];
        #pragma unroll
        for (int rt = 0; rt < 2; ++rt) {
            const int lr0 = wv * 32 + rt * 16 + nidx;
            const int arow = rows_lds[lr0];
            const float* xrow = x + (size_t)arow * DIM + g * 8;
            float xv[2][8];
            #pragma unroll
            for (int s = 0; s < 2; ++s) {
                float4 q0 = *(const float4*)(xrow + s * 32);
                float4 q1 = *(const float4*)(xrow + s * 32 + 4);
                xv[s][0] = q0.x; xv[s][1] = q0.y; xv[s][2] = q0.z; xv[s][3] = q0.w;
                xv[s][4] = q1.x; xv[s][5] = q1.y; xv[s][6] = q1.z; xv[s][7] = q1.w;
            }
            float ss = 0.f;
            #pragma unroll
            for (int s = 0; s < 2; ++s)
                #pragma unroll
                for (int i = 0; i < 8; ++i) ss += xv[s][i] * xv[s][i];
            ss += __shfl_xor(ss, 16, 64);
            ss += __shfl_xor(ss, 32, 64);
            float nrm = fmaxf(sqrtf(ss), EPSF);
            float inv = 1.0f / nrm;
            if (g == 0) inv_lds[lr0] = inv;
            #pragma unroll
            for (int s = 0; s < 2; ++s)
                #pragma unroll
                for (int i = 0; i < 8; ++i) {
                    float v = xv[s][i] * inv;
                    _Float16 hi = (_Float16)v;
                    ah[rt][s][i] = hi;
                    al[rt][s][i] = (_Float16)(v - (float)hi);
                }
        }

        // register-direct 3-pass scan, depth-1 prefetch (R7 body)
        const _Float16* bbase = wf + (size_t)lane * 8;
        f16x8 cb0 = *(const f16x8*)(bbase);
        f16x8 cb1 = *(const f16x8*)(bbase + 512);
        f16x8 cb2 = *(const f16x8*)(bbase + 1024);
        f16x8 cb3 = *(const f16x8*)(bbase + 1536);
        float mval = msw[nidx];

        float best[2][4];
        int bt[2][4];
        #pragma unroll
        for (int rt = 0; rt < 2; ++rt)
            #pragma unroll
            for (int r = 0; r < 4; ++r) { best[rt][r] = -3.4e38f; bt[rt][r] = 0; }

        for (int t = 0; t < NT; ++t) {
            const _Float16* np = bbase + (size_t)(t + 1) * 2048;  // guard at t=63
            f16x8 nb0 = *(const f16x8*)(np);
            f16x8 nb1 = *(const f16x8*)(np + 512);
            f16x8 nb2 = *(const f16x8*)(np + 1024);
            f16x8 nb3 = *(const f16x8*)(np + 1536);
            float nmval = (t + 1 < NT) ? msw[(t + 1) * 16 + nidx] : 0.f;

            f32x4 acc0 = {mval, mval, mval, mval};
            f32x4 acc1 = acc0;
            MFMA_(ah[0][0], cb0, acc0); MFMA_(ah[1][0], cb0, acc1);
            MFMA_(ah[0][1], cb1, acc0); MFMA_(ah[1][1], cb1, acc1);
            MFMA_(al[0][0], cb0, acc0); MFMA_(al[1][0], cb0, acc1);
            MFMA_(al[0][1], cb1, acc0); MFMA_(al[1][1], cb1, acc1);
            MFMA_(ah[0][0], cb2, acc0); MFMA_(ah[1][0], cb2, acc1);
            MFMA_(ah[0][1], cb3, acc0); MFMA_(ah[1][1], cb3, acc1);

            #pragma unroll
            for (int r = 0; r < 4; ++r) {
                if (acc0[r] > best[0][r]) { best[0][r] = acc0[r]; bt[0][r] = t; }
                if (acc1[r] > best[1][r]) { best[1][r] = acc1[r]; bt[1][r] = t; }
            }
            cb0 = nb0; cb1 = nb1; cb2 = nb2; cb3 = nb3; mval = nmval;
        }

        #pragma unroll
        for (int rt = 0; rt < 2; ++rt)
            #pragma unroll
            for (int r = 0; r < 4; ++r) {
                float bb = best[rt][r];
                int bi = bt[rt][r] * 16 + nidx;
                #pragma unroll
                for (int off = 1; off <= 8; off <<= 1) {
                    float ob = __shfl_xor(bb, off, 64);
                    int oi = __shfl_xor(bi, off, 64);
                    if (ob > bb || (ob == bb && oi < bi)) { bb = ob; bi = oi; }
                }
                if (nidx == 0)
                    idx_lds[wv * 32 + rt * 16 + g * 4 + r] = bi;
            }
        __syncthreads();

        // epilogue: for changed rows, rewrite out_q/out_idx and loss delta
        const int lr = tid >> 1;
        if (lr < nrows) {
            const int row = rows_lds[lr];
            const int cn = idx_lds[lr];
            const int co = (int)out_idx[row];
            if (cn != co) {
                const int d0 = (tid & 1) * 32;
                const float invn = inv_lds[lr];
                const float4* xp = (const float4*)(x + (size_t)row * DIM + d0);
                const float4* qn = (const float4*)(wn + (size_t)cn * DIM + d0);
                const float4* qo = (const float4*)(wn + (size_t)co * DIM + d0);
                float4* op = (float4*)(out_q + (size_t)row * DIM + d0);
                #pragma unroll
                for (int i = 0; i < 8; ++i) {
                    float4 xv4 = xp[i];
                    float4 qnv = qn[i];
                    float4 qov = qo[i];
                    float xn0 = xv4.x * invn, xn1 = xv4.y * invn;
                    float xn2 = xv4.z * invn, xn3 = xv4.w * invn;
                    float a0 = qnv.x - xn0, a1 = qnv.y - xn1,
                          a2 = qnv.z - xn2, a3 = qnv.w - xn3;
                    float c0 = qov.x - xn0, c1 = qov.y - xn1,
                          c2 = qov.z - xn2, c3 = qov.w - xn3;
                    dsum += (a0 * a0 + a1 * a1 + a2 * a2 + a3 * a3)
                          - (c0 * c0 + c1 * c1 + c2 * c2 + c3 * c3);
                    op[i] = qnv;
                }
                if (!(tid & 1)) out_idx[row] = (float)cn;
            }
        }
        __syncthreads();
    }

    // block-reduce dsum -> partial2[blockIdx.x]
    float s = dsum;
    #pragma unroll
    for (int off = 32; off; off >>= 1) s += __shfl_xor(s, off, 64);
    if (lane == 0) red[wv] = s;
    __syncthreads();
    if (tid == 0) partial2[blockIdx.x] = (red[0] + red[1]) + (red[2] + red[3]);
}

__global__ __launch_bounds__(256) void finalize_kernel(
    const float* __restrict__ partial, const float* __restrict__ partial2,
    float* __restrict__ loss_out)
{
    __shared__ float red[4];
    int t = threadIdx.x;
    float s = 0.f;
    #pragma unroll
    for (int i = 0; i < 8; ++i) s += partial[t * 8 + i];  // fixed order
    s += partial2[t];
    #pragma unroll
    for (int off = 32; off; off >>= 1) s += __shfl_xor(s, off, 64);
    if ((t & 63) == 0) red[t >> 6] = s;
    __syncthreads();
    if (t == 0)
        *loss_out = 1.25f * (((red[0] + red[1]) + (red[2] + red[3]))
                             / (float)((size_t)N_ROWS * DIM));
}

extern "C" void kernel_launch(void* const* d_in, const int* in_sizes, int n_in,
                              void* d_out, int out_size, void* d_ws, size_t ws_size,
                              hipStream_t stream) {
    const float* x = (const float*)d_in[0];   // [N, D]
    const float* w = (const float*)d_in[1];   // [K, D]
    float* out = (float*)d_out;
    float* ws = (float*)d_ws;

    float* wn       = ws;                                  // 65536
    float* msw      = wn + (size_t)K_CODES * DIM;          // 1024
    float* partial  = msw + K_CODES;                       // 2048
    float* partial2 = partial + 2048;                      // 256
    int*   counter  = (int*)(partial2 + 256);              // 1
    int*   list     = counter + 1;                         // 262144
    _Float16* wf    = (_Float16*)(ws + 331012);            // 68*2048 halves

    float* out_q    = out;
    float* out_loss = out + (size_t)N_ROWS * DIM;
    float* out_idx  = out_loss + 1;

    init_kernel<<<1, 64, 0, stream>>>(counter);
    prep_codebook<<<K_CODES, 64, 0, stream>>>(w, wn, msw, wf);
    vq_main_kernel<<<N_ROWS / ROWS_PER_BLOCK, 256, 0, stream>>>(
        x, wn, msw, wf, out_q, out_idx, partial, counter, list);
    fixup_kernel<<<256, 256, 0, stream>>>(
        x, wn, msw, wf, counter, list, out_q, out_idx, partial2);
    finalize_kernel<<<1, 256, 0, stream>>>(partial, partial2, out_loss);
}

// Round 18
// 242.678 us; speedup vs baseline: 1.0197x; 1.0197x over previous
//
#include <hip/hip_runtime.h>
#include <math.h>

#define N_ROWS 262144
#define DIM 64
#define K_CODES 1024
#define NT 64                 // code tiles of 16
#define ROWS_PER_BLOCK 128
#define EPSF 1e-12f
#define MARGIN 2.0e-3f        // 2*E, E = rigorous hh-score error bound (9.9e-4)

typedef _Float16 f16x8 __attribute__((ext_vector_type(8)));
typedef float f32x4 __attribute__((ext_vector_type(4)));

// ws layout (floats):
//   wn      : [0, 65536)           normalized codebook fp32
//   msw     : [65536, 66560)       -0.5 * sum(wn^2) per code
//   partial : [66560, 68608)       per-main-block loss partials (2048)
//   partial2: [68608, 68864)       per-fixup-block loss deltas (256)
//   counter : [68864]              (int) flagged-row count
//   list    : [68865, 331009)      (int) flagged row ids
//   wf      : from 331012          codebook hi/lo f16, 16x16x32 B-frag order
//             per 16-code tile t: 2048 halves:
//               [0,512)=hi s0 [512,1024)=hi s1 [1024,1536)=lo s0 [1536,2048)=lo s1
//             within each 512: lane(= g*16 + code%16)*8 + i, k-dim = s*32+g*8+i
//             +4 uninitialized guard tiles (prefetch targets, never consumed)

__global__ void init_kernel(int* counter) {
    if (threadIdx.x == 0) *counter = 0;
}

__global__ __launch_bounds__(64) void prep_codebook(
    const float* __restrict__ w, float* __restrict__ wn,
    float* __restrict__ msw, _Float16* __restrict__ wf)
{
    int k = blockIdx.x;
    int d = threadIdx.x;
    float v = w[k * DIM + d];
    float sq = v * v;
    #pragma unroll
    for (int off = 32; off; off >>= 1) sq += __shfl_xor(sq, off, 64);
    float n = fmaxf(sqrtf(sq), EPSF);
    float o = v / n;
    wn[k * DIM + d] = o;
    float s2 = o * o;
    #pragma unroll
    for (int off = 32; off; off >>= 1) s2 += __shfl_xor(s2, off, 64);
    if (d == 0) msw[k] = -0.5f * s2;

    _Float16 hi = (_Float16)o;
    _Float16 lo = (_Float16)(o - (float)hi);
    int t = k >> 4, nn = k & 15, s = d >> 5, g = (d >> 3) & 3, i = d & 7;
    size_t base = (size_t)t * 2048 + (size_t)s * 512 + (size_t)(g * 16 + nn) * 8 + i;
    wf[base] = hi;            // h = 0
    wf[base + 1024] = lo;     // h = 1
}

#define MFMA_(A, B, C) C = __builtin_amdgcn_mfma_f32_16x16x32_f16(A, B, C, 0, 0, 0)

// ------------------- main kernel: hi*hi prefilter, register-direct -------------------
// R7 skeleton: no in-loop barriers, depth-1 prefetch; 32 codes (2 subtiles) per
// iteration so one iteration carries 4x16B loads + 8 MFMA — half the iteration
// count of the proven 124us R7 loop.
__global__ __launch_bounds__(256, 4) void vq_main_kernel(
    const float* __restrict__ x,
    const float* __restrict__ wn,
    const float* __restrict__ msw,
    const _Float16* __restrict__ wf,
    float* __restrict__ out_q,
    float* __restrict__ out_idx,
    float* __restrict__ partial,
    int* __restrict__ counter,
    int* __restrict__ list)
{
    __shared__ float msw_lds[K_CODES + 32];   // +32 zero guard for last prefetch
    __shared__ int idx_lds[ROWS_PER_BLOCK];
    __shared__ float inv_lds[ROWS_PER_BLOCK];
    __shared__ float red[4];

    const int tid = threadIdx.x;              // 0..255 (4 waves)
    const int wv = tid >> 6;
    const int lane = tid & 63;
    const int nidx = lane & 15;
    const int g = lane >> 4;
    const int block_row0 = blockIdx.x * ROWS_PER_BLOCK;

    // ---- prologue: 32 rows/wave, normalize, hi A-frags only ----
    f16x8 ah[2][2];
    #pragma unroll
    for (int rt = 0; rt < 2; ++rt) {
        const int arow = block_row0 + wv * 32 + rt * 16 + nidx;
        const float* xrow = x + (size_t)arow * DIM + g * 8;
        float xv[2][8];
        #pragma unroll
        for (int s = 0; s < 2; ++s) {
            float4 q0 = *(const float4*)(xrow + s * 32);
            float4 q1 = *(const float4*)(xrow + s * 32 + 4);
            xv[s][0] = q0.x; xv[s][1] = q0.y; xv[s][2] = q0.z; xv[s][3] = q0.w;
            xv[s][4] = q1.x; xv[s][5] = q1.y; xv[s][6] = q1.z; xv[s][7] = q1.w;
        }
        float ss = 0.f;
        #pragma unroll
        for (int s = 0; s < 2; ++s)
            #pragma unroll
            for (int i = 0; i < 8; ++i) ss += xv[s][i] * xv[s][i];
        ss += __shfl_xor(ss, 16, 64);
        ss += __shfl_xor(ss, 32, 64);
        float nrm = fmaxf(sqrtf(ss), EPSF);
        float inv = 1.0f / nrm;
        if (g == 0) inv_lds[wv * 32 + rt * 16 + nidx] = inv;
        #pragma unroll
        for (int s = 0; s < 2; ++s)
            #pragma unroll
            for (int i = 0; i < 8; ++i)
                ah[rt][s][i] = (_Float16)(xv[s][i] * inv);
    }

    // ---- stage msw into LDS (+zero guard) ----
    *(float4*)&msw_lds[tid * 4] = *(const float4*)(msw + tid * 4);
    if (tid < 8) {
        float4 z = {0.f, 0.f, 0.f, 0.f};
        *(float4*)&msw_lds[K_CODES + tid * 4] = z;
    }

    // ---- preload subtiles 0,1 (hi regions) from global; mval from global ----
    const _Float16* bbase = wf + (size_t)lane * 8;
    f16x8 cb0 = *(const f16x8*)(bbase);                 // st0 hi s0
    f16x8 cb1 = *(const f16x8*)(bbase + 512);           // st0 hi s1
    f16x8 cb2 = *(const f16x8*)(bbase + 2048);          // st1 hi s0
    f16x8 cb3 = *(const f16x8*)(bbase + 2048 + 512);    // st1 hi s1
    float mv0 = msw[nidx];
    float mv1 = msw[16 + nidx];
    __syncthreads();                                    // msw_lds visible

    float b1v[2][4], b2v[2][4];
    int bti[2][4];
    #pragma unroll
    for (int rt = 0; rt < 2; ++rt)
        #pragma unroll
        for (int r = 0; r < 4; ++r) {
            b1v[rt][r] = -3.4e38f; b2v[rt][r] = -3.4e38f; bti[rt][r] = 0;
        }

    // ---- main loop: 32 iterations x 32 codes, no barriers, depth-1 prefetch ----
    const _Float16* gnext = bbase + 2 * 2048;
    const float* mnext = &msw_lds[32 + nidx];
    for (int it = 0; it < 32; ++it) {
        // prefetch subtiles 2it+2, 2it+3 (guard tiles make it=31 safe; unused)
        f16x8 nb0 = *(const f16x8*)(gnext);
        f16x8 nb1 = *(const f16x8*)(gnext + 512);
        f16x8 nb2 = *(const f16x8*)(gnext + 2048);
        f16x8 nb3 = *(const f16x8*)(gnext + 2048 + 512);
        gnext += 2 * 2048;
        float nm0 = mnext[0];
        float nm1 = mnext[16];
        mnext += 32;

        // subtile 2it
        f32x4 a0 = {mv0, mv0, mv0, mv0};
        f32x4 a1 = a0;
        __builtin_amdgcn_s_setprio(1);
        MFMA_(ah[0][0], cb0, a0); MFMA_(ah[1][0], cb0, a1);
        MFMA_(ah[0][1], cb1, a0); MFMA_(ah[1][1], cb1, a1);
        __builtin_amdgcn_s_setprio(0);
        #pragma unroll
        for (int r = 0; r < 4; ++r) {
            float s0 = a0[r], s1 = a1[r];
            b2v[0][r] = fmaxf(b2v[0][r], fminf(s0, b1v[0][r]));
            if (s0 > b1v[0][r]) { b1v[0][r] = s0; bti[0][r] = 2 * it; }
            b2v[1][r] = fmaxf(b2v[1][r], fminf(s1, b1v[1][r]));
            if (s1 > b1v[1][r]) { b1v[1][r] = s1; bti[1][r] = 2 * it; }
        }

        // subtile 2it+1
        f32x4 c0 = {mv1, mv1, mv1, mv1};
        f32x4 c1 = c0;
        __builtin_amdgcn_s_setprio(1);
        MFMA_(ah[0][0], cb2, c0); MFMA_(ah[1][0], cb2, c1);
        MFMA_(ah[0][1], cb3, c0); MFMA_(ah[1][1], cb3, c1);
        __builtin_amdgcn_s_setprio(0);
        #pragma unroll
        for (int r = 0; r < 4; ++r) {
            float s0 = c0[r], s1 = c1[r];
            b2v[0][r] = fmaxf(b2v[0][r], fminf(s0, b1v[0][r]));
            if (s0 > b1v[0][r]) { b1v[0][r] = s0; bti[0][r] = 2 * it + 1; }
            b2v[1][r] = fmaxf(b2v[1][r], fminf(s1, b1v[1][r]));
            if (s1 > b1v[1][r]) { b1v[1][r] = s1; bti[1][r] = 2 * it + 1; }
        }

        cb0 = nb0; cb1 = nb1; cb2 = nb2; cb3 = nb3;
        mv0 = nm0; mv1 = nm1;
    }

    // ---- top-2 butterfly across the 16 lanes holding each row ----
    #pragma unroll
    for (int rt = 0; rt < 2; ++rt)
        #pragma unroll
        for (int r = 0; r < 4; ++r) {
            float b1 = b1v[rt][r], b2 = b2v[rt][r];
            int i1 = bti[rt][r] * 16 + nidx;
            #pragma unroll
            for (int off = 1; off <= 8; off <<= 1) {
                float ob1 = __shfl_xor(b1, off, 64);
                int   oi1 = __shfl_xor(i1, off, 64);
                float ob2 = __shfl_xor(b2, off, 64);
                float loser = fminf(b1, ob1);
                b2 = fmaxf(fmaxf(b2, ob2), loser);
                if (ob1 > b1 || (ob1 == b1 && oi1 < i1)) { b1 = ob1; i1 = oi1; }
            }
            if (nidx == 0) {
                const int lrow = wv * 32 + rt * 16 + g * 4 + r;
                idx_lds[lrow] = i1;
                if (b1 - b2 <= MARGIN) {          // ambiguous: exact fixup
                    int pos = atomicAdd(counter, 1);
                    list[pos] = block_row0 + lrow;
                }
            }
        }
    __syncthreads();

    // ---- epilogue: gather fp32 codebook row, write out, loss partial ----
    const int lr = tid >> 1;
    const int grow = block_row0 + lr;
    const int d0 = (tid & 1) * 32;
    const int ci = idx_lds[lr];
    const float invn = inv_lds[lr];
    const float4* xp = (const float4*)(x + (size_t)grow * DIM + d0);
    const float4* qp = (const float4*)(wn + (size_t)ci * DIM + d0);
    float4* op = (float4*)(out_q + (size_t)grow * DIM + d0);
    float ls = 0.f;
    #pragma unroll
    for (int i = 0; i < 8; ++i) {
        float4 qv = qp[i];
        float4 xv4 = xp[i];
        float e0 = qv.x - xv4.x * invn;
        float e1 = qv.y - xv4.y * invn;
        float e2 = qv.z - xv4.z * invn;
        float e3 = qv.w - xv4.w * invn;
        ls += e0 * e0 + e1 * e1 + e2 * e2 + e3 * e3;
        op[i] = qv;
    }
    if (!(tid & 1)) out_idx[grow] = (float)ci;

    float s = ls;
    #pragma unroll
    for (int off = 32; off; off >>= 1) s += __shfl_xor(s, off, 64);
    if (lane == 0) red[wv] = s;
    __syncthreads();
    if (tid == 0) partial[blockIdx.x] = (red[0] + red[1]) + (red[2] + red[3]);
}

// ------------------- fixup: exact 3-pass rescore of flagged rows -------------------
__global__ __launch_bounds__(256, 4) void fixup_kernel(
    const float* __restrict__ x,
    const float* __restrict__ wn,
    const float* __restrict__ msw,
    const _Float16* __restrict__ wf,
    const int* __restrict__ counter,
    const int* __restrict__ list,
    float* __restrict__ out_q,
    float* __restrict__ out_idx,
    float* __restrict__ partial2)
{
    __shared__ int rows_lds[128];
    __shared__ int idx_lds[128];
    __shared__ float inv_lds[128];
    __shared__ float red[4];

    const int tid = threadIdx.x;
    const int wv = tid >> 6;
    const int lane = tid & 63;
    const int nidx = lane & 15;
    const int g = lane >> 4;
    const int cnt = *counter;
    float dsum = 0.f;

    for (int b = blockIdx.x; b * 128 < cnt; b += gridDim.x) {
        const int rbase = b * 128;
        const int nrows = min(128, cnt - rbase);
        __syncthreads();
        if (tid < 128) rows_lds[tid] = list[rbase + min(tid, nrows - 1)];
        __syncthreads();

        // prologue: gather 32 rows/wave, hi+lo A-frags
        f16x8 ah[2][2], al[2][2];
        #pragma unroll
        for (int rt = 0; rt < 2; ++rt) {
            const int lr0 = wv * 32 + rt * 16 + nidx;
            const int arow = rows_lds[lr0];
            const float* xrow = x + (size_t)arow * DIM + g * 8;
            float xv[2][8];
            #pragma unroll
            for (int s = 0; s < 2; ++s) {
                float4 q0 = *(const float4*)(xrow + s * 32);
                float4 q1 = *(const float4*)(xrow + s * 32 + 4);
                xv[s][0] = q0.x; xv[s][1] = q0.y; xv[s][2] = q0.z; xv[s][3] = q0.w;
                xv[s][4] = q1.x; xv[s][5] = q1.y; xv[s][6] = q1.z; xv[s][7] = q1.w;
            }
            float ss = 0.f;
            #pragma unroll
            for (int s = 0; s < 2; ++s)
                #pragma unroll
                for (int i = 0; i < 8; ++i) ss += xv[s][i] * xv[s][i];
            ss += __shfl_xor(ss, 16, 64);
            ss += __shfl_xor(ss, 32, 64);
            float nrm = fmaxf(sqrtf(ss), EPSF);
            float inv = 1.0f / nrm;
            if (g == 0) inv_lds[lr0] = inv;
            #pragma unroll
            for (int s = 0; s < 2; ++s)
                #pragma unroll
                for (int i = 0; i < 8; ++i) {
                    float v = xv[s][i] * inv;
                    _Float16 hi = (_Float16)v;
                    ah[rt][s][i] = hi;
                    al[rt][s][i] = (_Float16)(v - (float)hi);
                }
        }

        // register-direct 3-pass scan, depth-1 prefetch (R7 body)
        const _Float16* bbase = wf + (size_t)lane * 8;
        f16x8 cb0 = *(const f16x8*)(bbase);
        f16x8 cb1 = *(const f16x8*)(bbase + 512);
        f16x8 cb2 = *(const f16x8*)(bbase + 1024);
        f16x8 cb3 = *(const f16x8*)(bbase + 1536);
        float mval = msw[nidx];

        float best[2][4];
        int bt[2][4];
        #pragma unroll
        for (int rt = 0; rt < 2; ++rt)
            #pragma unroll
            for (int r = 0; r < 4; ++r) { best[rt][r] = -3.4e38f; bt[rt][r] = 0; }

        for (int t = 0; t < NT; ++t) {
            const _Float16* np = bbase + (size_t)(t + 1) * 2048;  // guard at t=63
            f16x8 nb0 = *(const f16x8*)(np);
            f16x8 nb1 = *(const f16x8*)(np + 512);
            f16x8 nb2 = *(const f16x8*)(np + 1024);
            f16x8 nb3 = *(const f16x8*)(np + 1536);
            float nmval = (t + 1 < NT) ? msw[(t + 1) * 16 + nidx] : 0.f;

            f32x4 acc0 = {mval, mval, mval, mval};
            f32x4 acc1 = acc0;
            MFMA_(ah[0][0], cb0, acc0); MFMA_(ah[1][0], cb0, acc1);
            MFMA_(ah[0][1], cb1, acc0); MFMA_(ah[1][1], cb1, acc1);
            MFMA_(al[0][0], cb0, acc0); MFMA_(al[1][0], cb0, acc1);
            MFMA_(al[0][1], cb1, acc0); MFMA_(al[1][1], cb1, acc1);
            MFMA_(ah[0][0], cb2, acc0); MFMA_(ah[1][0], cb2, acc1);
            MFMA_(ah[0][1], cb3, acc0); MFMA_(ah[1][1], cb3, acc1);

            #pragma unroll
            for (int r = 0; r < 4; ++r) {
                if (acc0[r] > best[0][r]) { best[0][r] = acc0[r]; bt[0][r] = t; }
                if (acc1[r] > best[1][r]) { best[1][r] = acc1[r]; bt[1][r] = t; }
            }
            cb0 = nb0; cb1 = nb1; cb2 = nb2; cb3 = nb3; mval = nmval;
        }

        #pragma unroll
        for (int rt = 0; rt < 2; ++rt)
            #pragma unroll
            for (int r = 0; r < 4; ++r) {
                float bb = best[rt][r];
                int bi = bt[rt][r] * 16 + nidx;
                #pragma unroll
                for (int off = 1; off <= 8; off <<= 1) {
                    float ob = __shfl_xor(bb, off, 64);
                    int oi = __shfl_xor(bi, off, 64);
                    if (ob > bb || (ob == bb && oi < bi)) { bb = ob; bi = oi; }
                }
                if (nidx == 0)
                    idx_lds[wv * 32 + rt * 16 + g * 4 + r] = bi;
            }
        __syncthreads();

        // epilogue: for changed rows, rewrite out_q/out_idx and loss delta
        const int lr = tid >> 1;
        if (lr < nrows) {
            const int row = rows_lds[lr];
            const int cn = idx_lds[lr];
            const int co = (int)out_idx[row];
            if (cn != co) {
                const int d0 = (tid & 1) * 32;
                const float invn = inv_lds[lr];
                const float4* xp = (const float4*)(x + (size_t)row * DIM + d0);
                const float4* qn = (const float4*)(wn + (size_t)cn * DIM + d0);
                const float4* qo = (const float4*)(wn + (size_t)co * DIM + d0);
                float4* op = (float4*)(out_q + (size_t)row * DIM + d0);
                #pragma unroll
                for (int i = 0; i < 8; ++i) {
                    float4 xv4 = xp[i];
                    float4 qnv = qn[i];
                    float4 qov = qo[i];
                    float xn0 = xv4.x * invn, xn1 = xv4.y * invn;
                    float xn2 = xv4.z * invn, xn3 = xv4.w * invn;
                    float a0 = qnv.x - xn0, a1 = qnv.y - xn1,
                          a2 = qnv.z - xn2, a3 = qnv.w - xn3;
                    float c0 = qov.x - xn0, c1 = qov.y - xn1,
                          c2 = qov.z - xn2, c3 = qov.w - xn3;
                    dsum += (a0 * a0 + a1 * a1 + a2 * a2 + a3 * a3)
                          - (c0 * c0 + c1 * c1 + c2 * c2 + c3 * c3);
                    op[i] = qnv;
                }
                if (!(tid & 1)) out_idx[row] = (float)cn;
            }
        }
        __syncthreads();
    }

    // block-reduce dsum -> partial2[blockIdx.x]
    float s = dsum;
    #pragma unroll
    for (int off = 32; off; off >>= 1) s += __shfl_xor(s, off, 64);
    if (lane == 0) red[wv] = s;
    __syncthreads();
    if (tid == 0) partial2[blockIdx.x] = (red[0] + red[1]) + (red[2] + red[3]);
}

__global__ __launch_bounds__(256) void finalize_kernel(
    const float* __restrict__ partial, const float* __restrict__ partial2,
    float* __restrict__ loss_out)
{
    __shared__ float red[4];
    int t = threadIdx.x;
    float s = 0.f;
    #pragma unroll
    for (int i = 0; i < 8; ++i) s += partial[t * 8 + i];  // fixed order
    s += partial2[t];
    #pragma unroll
    for (int off = 32; off; off >>= 1) s += __shfl_xor(s, off, 64);
    if ((t & 63) == 0) red[t >> 6] = s;
    __syncthreads();
    if (t == 0)
        *loss_out = 1.25f * (((red[0] + red[1]) + (red[2] + red[3]))
                             / (float)((size_t)N_ROWS * DIM));
}

extern "C" void kernel_launch(void* const* d_in, const int* in_sizes, int n_in,
                              void* d_out, int out_size, void* d_ws, size_t ws_size,
                              hipStream_t stream) {
    const float* x = (const float*)d_in[0];   // [N, D]
    const float* w = (const float*)d_in[1];   // [K, D]
    float* out = (float*)d_out;
    float* ws = (float*)d_ws;

    float* wn       = ws;                                  // 65536
    float* msw      = wn + (size_t)K_CODES * DIM;          // 1024
    float* partial  = msw + K_CODES;                       // 2048
    float* partial2 = partial + 2048;                      // 256
    int*   counter  = (int*)(partial2 + 256);              // 1
    int*   list     = counter + 1;                         // 262144
    _Float16* wf    = (_Float16*)(ws + 331012);            // 68*2048 halves

    float* out_q    = out;
    float* out_loss = out + (size_t)N_ROWS * DIM;
    float* out_idx  = out_loss + 1;

    init_kernel<<<1, 64, 0, stream>>>(counter);
    prep_codebook<<<K_CODES, 64, 0, stream>>>(w, wn, msw, wf);
    vq_main_kernel<<<N_ROWS / ROWS_PER_BLOCK, 256, 0, stream>>>(
        x, wn, msw, wf, out_q, out_idx, partial, counter, list);
    fixup_kernel<<<256, 256, 0, stream>>>(
        x, wn, msw, wf, counter, list, out_q, out_idx, partial2);
    finalize_kernel<<<1, 256, 0, stream>>>(partial, partial2, out_loss);
}

// Round 19
// 118.820 us; speedup vs baseline: 2.0827x; 2.0424x over previous
//
#include <hip/hip_runtime.h>
#include <math.h>

#define N_ROWS 262144
#define DIM 64
#define K_CODES 1024
#define NT2 32                // code supertiles of 32
#define ROWS_PER_BLOCK 128
#define EPSF 1e-12f

typedef _Float16 f16x8 __attribute__((ext_vector_type(8)));
typedef float f32x4 __attribute__((ext_vector_type(4)));

// ws layout (floats):
//   wn      : [0, 65536)         normalized codebook fp32 (gather/epilogue)
//   msw     : [65536, 66560)     -0.5 * sum(wn^2) per code
//   partial : [66560, 68608)     per-block loss partials (2048)
//   wf      : halves after that  codebook hi/lo f16, 16x16x32 B-fragment order
//             per 16-code tile t: 2048 halves:
//               [0,512)=hi s0  [512,1024)=hi s1  [1024,1536)=lo s0  [1536,2048)=lo s1
//             within each 512: lane(= g*16 + code%16)*8 + i,  k-dim = s*32+g*8+i
//             a 32-code supertile = two consecutive 16-code tiles (4096 halves)

__global__ __launch_bounds__(64) void prep_codebook(
    const float* __restrict__ w, float* __restrict__ wn,
    float* __restrict__ msw, _Float16* __restrict__ wf)
{
    int k = blockIdx.x;
    int d = threadIdx.x;
    float v = w[k * DIM + d];
    float sq = v * v;
    #pragma unroll
    for (int off = 32; off; off >>= 1) sq += __shfl_xor(sq, off, 64);
    float n = fmaxf(sqrtf(sq), EPSF);
    float o = v / n;
    wn[k * DIM + d] = o;
    float s2 = o * o;
    #pragma unroll
    for (int off = 32; off; off >>= 1) s2 += __shfl_xor(s2, off, 64);
    if (d == 0) msw[k] = -0.5f * s2;

    _Float16 hi = (_Float16)o;
    _Float16 lo = (_Float16)(o - (float)hi);
    // B fragment for 16x16x32: lane = g*16 + n holds k-dims s*32 + g*8 + i
    int t = k >> 4, nn = k & 15, s = d >> 5, g = (d >> 3) & 3, i = d & 7;
    size_t base = (size_t)t * 2048 + (size_t)s * 512 + (size_t)(g * 16 + nn) * 8 + i;
    wf[base] = hi;            // h = 0
    wf[base + 1024] = lo;     // h = 1
}

#define MFMA_(A, B, C) C = __builtin_amdgcn_mfma_f32_16x16x32_f16(A, B, C, 0, 0, 0)

__global__ __launch_bounds__(256, 4) void vq_main_kernel(
    const float* __restrict__ x,
    const float* __restrict__ wn,
    const float* __restrict__ msw,
    const _Float16* __restrict__ wf,
    float* __restrict__ out_q,
    float* __restrict__ out_idx,
    float* __restrict__ partial)
{
    __shared__ _Float16 bbuf[2][4096];        // double-buffered 8 KB supertiles
    __shared__ float msw_lds[K_CODES];
    __shared__ int idx_lds[ROWS_PER_BLOCK];
    __shared__ float inv_lds[ROWS_PER_BLOCK];
    __shared__ float red[4];

    const int tid = threadIdx.x;              // 0..255 (4 waves)
    const int wv = tid >> 6;
    const int lane = tid & 63;
    const int nidx = lane & 15;       // code-within-16 / x-row-within-rowtile
    const int g = lane >> 4;          // k-group
    const int block_row0 = blockIdx.x * ROWS_PER_BLOCK;

    // ---- prologue: 32 rows/wave (2 row-tiles of 16), normalize, hi/lo A-frags ----
    // A for 16x16x32: lane = g*16+m holds A[m][k = g*8+i] (+s*32 per kstep)
    f16x8 ah[2][2], al[2][2];
    #pragma unroll
    for (int rt = 0; rt < 2; ++rt) {
        const int arow = block_row0 + wv * 32 + rt * 16 + nidx;
        const float* xrow = x + (size_t)arow * DIM + g * 8;
        float xv[2][8];
        #pragma unroll
        for (int s = 0; s < 2; ++s) {
            float4 q0 = *(const float4*)(xrow + s * 32);
            float4 q1 = *(const float4*)(xrow + s * 32 + 4);
            xv[s][0] = q0.x; xv[s][1] = q0.y; xv[s][2] = q0.z; xv[s][3] = q0.w;
            xv[s][4] = q1.x; xv[s][5] = q1.y; xv[s][6] = q1.z; xv[s][7] = q1.w;
        }
        float ss = 0.f;
        #pragma unroll
        for (int s = 0; s < 2; ++s)
            #pragma unroll
            for (int i = 0; i < 8; ++i) ss += xv[s][i] * xv[s][i];
        ss += __shfl_xor(ss, 16, 64);  // sum across the 4 k-groups of this row
        ss += __shfl_xor(ss, 32, 64);
        float nrm = fmaxf(sqrtf(ss), EPSF);
        float inv = 1.0f / nrm;
        if (g == 0) inv_lds[wv * 32 + rt * 16 + nidx] = inv;
        #pragma unroll
        for (int s = 0; s < 2; ++s)
            #pragma unroll
            for (int i = 0; i < 8; ++i) {
                float v = xv[s][i] * inv;
                _Float16 hi = (_Float16)v;
                ah[rt][s][i] = hi;
                al[rt][s][i] = (_Float16)(v - (float)hi);
            }
    }

    // ---- stage msw into LDS, conflict-free 16B/thread ----
    *(float4*)&msw_lds[tid * 4] = *(const float4*)(msw + tid * 4);

    // ---- stage supertile 0 into bbuf[0]; prefetch supertile 1 into regs ----
    {
        f16x8 sa = *(const f16x8*)(wf + tid * 8);
        f16x8 sb = *(const f16x8*)(wf + 2048 + tid * 8);
        *(f16x8*)&bbuf[0][tid * 8] = sa;
        *(f16x8*)&bbuf[0][2048 + tid * 8] = sb;
    }
    f16x8 stg0 = *(const f16x8*)(wf + 4096 + tid * 8);
    f16x8 stg1 = *(const f16x8*)(wf + 4096 + 2048 + tid * 8);
    const _Float16* gnext = wf + 8192 + (size_t)tid * 8;   // supertile 2
    __syncthreads();

    float best[2][4];
    int bt[2][4];
    #pragma unroll
    for (int rt = 0; rt < 2; ++rt)
        #pragma unroll
        for (int r = 0; r < 4; ++r) { best[rt][r] = -3.4e38f; bt[rt][r] = 0; }

    // ---- main loop: 32 supertiles (32 codes each), LDS double-buffer ----
    for (int t = 0; t < NT2; ++t) {
        const int cur = t & 1;
        const _Float16* bp = &bbuf[cur][lane * 8];
        // code-group 0 (codes t*32 .. t*32+15)
        f16x8 bh0 = *(const f16x8*)(bp);
        f16x8 bh1 = *(const f16x8*)(bp + 512);
        f16x8 bl0 = *(const f16x8*)(bp + 1024);
        f16x8 bl1 = *(const f16x8*)(bp + 1536);
        // code-group 1 (codes t*32+16 .. t*32+31)
        f16x8 bh2 = *(const f16x8*)(bp + 2048);
        f16x8 bh3 = *(const f16x8*)(bp + 2560);
        f16x8 bl2 = *(const f16x8*)(bp + 3072);
        f16x8 bl3 = *(const f16x8*)(bp + 3584);
        float mv0 = msw_lds[t * 32 + nidx];
        float mv1 = msw_lds[t * 32 + 16 + nidx];

        f32x4 a00 = {mv0, mv0, mv0, mv0};   // rt0, cg0
        f32x4 a01 = a00;                    // rt1, cg0
        f32x4 a10 = {mv1, mv1, mv1, mv1};   // rt0, cg1
        f32x4 a11 = a10;                    // rt1, cg1
        __builtin_amdgcn_s_setprio(1);
        // 24 MFMA: 4 independent depth-6 chains (rt x cg)
        MFMA_(ah[0][0], bh0, a00); MFMA_(ah[1][0], bh0, a01);
        MFMA_(ah[0][0], bh2, a10); MFMA_(ah[1][0], bh2, a11);
        MFMA_(ah[0][1], bh1, a00); MFMA_(ah[1][1], bh1, a01);
        MFMA_(ah[0][1], bh3, a10); MFMA_(ah[1][1], bh3, a11);
        MFMA_(al[0][0], bh0, a00); MFMA_(al[1][0], bh0, a01);
        MFMA_(al[0][0], bh2, a10); MFMA_(al[1][0], bh2, a11);
        MFMA_(al[0][1], bh1, a00); MFMA_(al[1][1], bh1, a01);
        MFMA_(al[0][1], bh3, a10); MFMA_(al[1][1], bh3, a11);
        MFMA_(ah[0][0], bl0, a00); MFMA_(ah[1][0], bl0, a01);
        MFMA_(ah[0][0], bl2, a10); MFMA_(ah[1][0], bl2, a11);
        MFMA_(ah[0][1], bl1, a00); MFMA_(ah[1][1], bl1, a01);
        MFMA_(ah[0][1], bl3, a10); MFMA_(ah[1][1], bl3, a11);
        __builtin_amdgcn_s_setprio(0);

        // write staged supertile t+1, then issue loads for t+2
        if (t + 1 < NT2) {
            *(f16x8*)&bbuf[cur ^ 1][tid * 8] = stg0;
            *(f16x8*)&bbuf[cur ^ 1][2048 + tid * 8] = stg1;
            if (t + 2 < NT2) {
                stg0 = *(const f16x8*)(gnext);
                stg1 = *(const f16x8*)(gnext + 2048);
                gnext += 4096;
            }
        }

        // compare: cg0 before cg1 (strict > => first-argmin tie semantics)
        #pragma unroll
        for (int r = 0; r < 4; ++r) {
            if (a00[r] > best[0][r]) { best[0][r] = a00[r]; bt[0][r] = t * 32; }
            if (a01[r] > best[1][r]) { best[1][r] = a01[r]; bt[1][r] = t * 32; }
            if (a10[r] > best[0][r]) { best[0][r] = a10[r]; bt[0][r] = t * 32 + 16; }
            if (a11[r] > best[1][r]) { best[1][r] = a11[r]; bt[1][r] = t * 32 + 16; }
        }
        __syncthreads();
    }

    // ---- argmax reduce across the 16 lanes holding each row ----
    // C 16x16: col = lane&15 (code), row = (lane>>4)*4 + r
    #pragma unroll
    for (int rt = 0; rt < 2; ++rt)
        #pragma unroll
        for (int r = 0; r < 4; ++r) {
            float b = best[rt][r];
            int bi = bt[rt][r] + nidx;
            #pragma unroll
            for (int off = 1; off <= 8; off <<= 1) {
                float ob = __shfl_xor(b, off, 64);
                int oi = __shfl_xor(bi, off, 64);
                if (ob > b || (ob == b && oi < bi)) { b = ob; bi = oi; }
            }
            if (nidx == 0)
                idx_lds[wv * 32 + rt * 16 + g * 4 + r] = bi;
        }
    __syncthreads();

    // ---- epilogue: gather fp32 codebook row, write out, loss partial ----
    const int lr = tid >> 1;
    const int grow = block_row0 + lr;
    const int d0 = (tid & 1) * 32;
    const int ci = idx_lds[lr];
    const float invn = inv_lds[lr];
    const float4* xp = (const float4*)(x + (size_t)grow * DIM + d0);
    const float4* qp = (const float4*)(wn + (size_t)ci * DIM + d0);
    float4* op = (float4*)(out_q + (size_t)grow * DIM + d0);
    float ls = 0.f;
    #pragma unroll
    for (int i = 0; i < 8; ++i) {
        float4 qv = qp[i];
        float4 xv4 = xp[i];
        float e0 = qv.x - xv4.x * invn;
        float e1 = qv.y - xv4.y * invn;
        float e2 = qv.z - xv4.z * invn;
        float e3 = qv.w - xv4.w * invn;
        ls += e0 * e0 + e1 * e1 + e2 * e2 + e3 * e3;
        op[i] = qv;
    }
    if (!(tid & 1)) out_idx[grow] = (float)ci;

    float s = ls;
    #pragma unroll
    for (int off = 32; off; off >>= 1) s += __shfl_xor(s, off, 64);
    if (lane == 0) red[wv] = s;
    __syncthreads();
    if (tid == 0) partial[blockIdx.x] = (red[0] + red[1]) + (red[2] + red[3]);
}

__global__ __launch_bounds__(256) void finalize_kernel(
    const float* __restrict__ partial, float* __restrict__ loss_out)
{
    __shared__ float red[4];
    int t = threadIdx.x;
    float s = 0.f;
    #pragma unroll
    for (int i = 0; i < 8; ++i) s += partial[t * 8 + i];  // fixed order
    #pragma unroll
    for (int off = 32; off; off >>= 1) s += __shfl_xor(s, off, 64);
    if ((t & 63) == 0) red[t >> 6] = s;
    __syncthreads();
    if (t == 0)
        *loss_out = 1.25f * (((red[0] + red[1]) + (red[2] + red[3]))
                             / (float)((size_t)N_ROWS * DIM));
}

extern "C" void kernel_launch(void* const* d_in, const int* in_sizes, int n_in,
                              void* d_out, int out_size, void* d_ws, size_t ws_size,
                              hipStream_t stream) {
    const float* x = (const float*)d_in[0];   // [N, D]
    const float* w = (const float*)d_in[1];   // [K, D]
    float* out = (float*)d_out;
    float* ws = (float*)d_ws;

    float* wn      = ws;                                   // 65536 floats
    float* msw     = wn + (size_t)K_CODES * DIM;           // 1024 floats
    float* partial = msw + K_CODES;                        // 2048 floats
    _Float16* wf   = (_Float16*)(partial + 2048);          // 64*2048 halves

    float* out_q    = out;                                 // [N*D]
    float* out_loss = out + (size_t)N_ROWS * DIM;          // [1]
    float* out_idx  = out_loss + 1;                        // [N]

    prep_codebook<<<K_CODES, 64, 0, stream>>>(w, wn, msw, wf);
    vq_main_kernel<<<N_ROWS / ROWS_PER_BLOCK, 256, 0, stream>>>(
        x, wn, msw, wf, out_q, out_idx, partial);
    finalize_kernel<<<1, 256, 0, stream>>>(partial, out_loss);
}